// Round 4
// baseline (511.199 us; speedup 1.0000x reference)
//
#include <hip/hip_runtime.h>
#include <cstdint>
#include <cstddef>

#define NEXPERT 32
#define KIN 256
#define NOUT 256
#define NTOK 524288
#define BM 64

typedef float f32x4 __attribute__((ext_vector_type(4)));
typedef __bf16 bf16x8 __attribute__((ext_vector_type(8)));
typedef unsigned short u16;
typedef u16 u16x8 __attribute__((ext_vector_type(8)));

union BF8 { u16x8 u; bf16x8 b; };

__device__ __forceinline__ u16 f2bf(float f) {
  unsigned u = __float_as_uint(f);
  return (u16)((u + 0x7FFFu + ((u >> 16) & 1u)) >> 16);  // RNE
}

// ---- pre-kernel: W fp32 -> bf16 into workspace ----
__global__ void conv_w_kernel(const float* __restrict__ w, u16* __restrict__ wb) {
  const int i = (blockIdx.x * 256 + threadIdx.x) * 4;
  const float4 v = *reinterpret_cast<const float4*>(w + i);
  ushort4 o;
  o.x = f2bf(v.x); o.y = f2bf(v.y); o.z = f2bf(v.z); o.w = f2bf(v.w);
  *reinterpret_cast<ushort4*>(wb + i) = o;
}

// ---- helpers ----
__device__ __forceinline__ void cvt8(const float4& x, const float4& y, BF8& o) {
  o.u[0]=f2bf(x.x); o.u[1]=f2bf(x.y); o.u[2]=f2bf(x.z); o.u[3]=f2bf(x.w);
  o.u[4]=f2bf(y.x); o.u[5]=f2bf(y.y); o.u[6]=f2bf(y.z); o.u[7]=f2bf(y.w);
}

// A-fragment raw loads for one K-chunk (K=32): lane reads rows (m*16+l15),
// 8 consecutive fp32 at k = cch*32 + lg*8.
__device__ __forceinline__ void loadA(const float* aBase, int cch, float4 (&r)[8]) {
#pragma unroll
  for (int m = 0; m < 4; ++m) {
    const float* p = aBase + (size_t)(m * 16) * KIN + cch * 32;
    r[2*m]   = *reinterpret_cast<const float4*>(p);
    r[2*m+1] = *reinterpret_cast<const float4*>(p + 4);
  }
}

template<bool WSBF>
__device__ __forceinline__ void loadB(const u16* wB, const float* wF, int cch, BF8 (&d)[4]) {
  if (WSBF) {
#pragma unroll
    for (int n = 0; n < 4; ++n)
      d[n].u = *reinterpret_cast<const u16x8*>(wB + n * (16 * KIN) + cch * 32);
  } else {
#pragma unroll
    for (int n = 0; n < 4; ++n) {
      const float4* p = reinterpret_cast<const float4*>(wF + n * (16 * KIN) + cch * 32);
      cvt8(p[0], p[1], d[n]);
    }
  }
}

// ---- barrier-free grouped GEMM ----
// block=256 (4 waves), tile BM=64 x BN=256; no LDS, no __syncthreads.
// A frags per-lane direct from global (4-wave reuse via L1); B from bf16 ws.
// K-chunks of 32, 1-chunk double-buffered prefetch of A-raw and B-frags.
template<bool WSBF>
__global__ __launch_bounds__(256)
void moe_gemm_kernel(const float* __restrict__ inp,
                     const float* __restrict__ w32,
                     const u16* __restrict__ wbf,
                     const int* __restrict__ counts,
                     float* __restrict__ out)
{
  const int tid  = threadIdx.x;
  const int lane = tid & 63;
  const int wv   = tid >> 6;   // 0..3 -> 64-col block
  const int l15  = lane & 15;
  const int lg   = lane >> 4;  // 0..3

  // ---- per-wave cumsum of counts via shuffle scan (no LDS, no barrier) ----
  const long long* c64 = reinterpret_cast<const long long*>(counts);
  const long long p0 = c64[0];
  const bool is64 = (p0 >= 0 && p0 < (1ll << 31));   // int64 vs int32 probe
  int c = 0;
  if (lane < 32) c = is64 ? (int)c64[lane] : counts[lane];
#pragma unroll
  for (int d = 1; d < 32; d <<= 1) {
    const int o = __shfl_up(c, d, 64);
    if (lane >= d) c += o;
  }
  const int cum = (lane < 32) ? c : 0x7fffffff;  // lane e holds cumsum[0..e]

  const int t0 = blockIdx.x * BM;
  const int t1 = t0 + BM;

  const float* aBase = inp + (size_t)(t0 + l15) * KIN + lg * 8;

  int rb = t0;
  int e  = __popcll(__ballot(cum <= t0));   // first expert covering t0

  while (rb < t1) {
    const int re = min(t1, __shfl(cum, e));
    if (re > rb) {
      const size_t wro = ((size_t)e << 16) + (size_t)((wv << 6) + l15) * KIN + lg * 8;
      const u16*   wB  = wbf + wro;
      const float* wF  = w32 + wro;

      f32x4 acc[4][4];
      const f32x4 zero = {0.f, 0.f, 0.f, 0.f};
#pragma unroll
      for (int m = 0; m < 4; ++m)
#pragma unroll
        for (int n = 0; n < 4; ++n) acc[m][n] = zero;

      float4 rawA[2][8];
      BF8    bfr[2][4];

      loadA(aBase, 0, rawA[0]);
      loadB<WSBF>(wB, wF, 0, bfr[0]);

#pragma unroll
      for (int cch = 0; cch < 8; ++cch) {       // 8 K-chunks of 32
        const int cur = cch & 1;                 // static after unroll
        const int nxt = cur ^ 1;
        if (cch < 7) {                           // issue next-chunk loads first
          loadA(aBase, cch + 1, rawA[nxt]);
          loadB<WSBF>(wB, wF, cch + 1, bfr[nxt]);
        }
        BF8 af[4];
#pragma unroll
        for (int m = 0; m < 4; ++m)
          cvt8(rawA[cur][2*m], rawA[cur][2*m+1], af[m]);
#pragma unroll
        for (int m = 0; m < 4; ++m)
#pragma unroll
          for (int n = 0; n < 4; ++n)
            acc[m][n] = __builtin_amdgcn_mfma_f32_16x16x32_bf16(
                af[m].b, bfr[cur][n].b, acc[m][n], 0, 0, 0);
      }

      // ---- epilogue (C/D map: col=l15, row=lg*4+j) ----
      const bool full = (rb == t0) & (re == t1);
      if (full) {
#pragma unroll
        for (int m = 0; m < 4; ++m) {
          const int rbase = t0 + (m << 4) + (lg << 2);
#pragma unroll
          for (int n = 0; n < 4; ++n) {
            float* op = out + (size_t)rbase * NOUT + (wv << 6) + (n << 4) + l15;
#pragma unroll
            for (int j = 0; j < 4; ++j) op[(size_t)j * NOUT] = acc[m][n][j];
          }
        }
      } else {
#pragma unroll
        for (int m = 0; m < 4; ++m) {
          const int rbase = t0 + (m << 4) + (lg << 2);
#pragma unroll
          for (int n = 0; n < 4; ++n) {
            float* op = out + (size_t)rbase * NOUT + (wv << 6) + (n << 4) + l15;
#pragma unroll
            for (int j = 0; j < 4; ++j) {
              const int rg = rbase + j;
              if (rg >= rb && rg < re) op[(size_t)j * NOUT] = acc[m][n][j];
            }
          }
        }
      }
    }
    rb = re > rb ? re : rb;
    ++e;
  }
}

extern "C" void kernel_launch(void* const* d_in, const int* in_sizes, int n_in,
                              void* d_out, int out_size, void* d_ws, size_t ws_size,
                              hipStream_t stream) {
  const float* inp    = (const float*)d_in[0];
  const float* w      = (const float*)d_in[1];
  const int*   counts = (const int*)d_in[2];
  float*       out    = (float*)d_out;

  const size_t wbytes = (size_t)NEXPERT * NOUT * KIN * 2;  // 4 MB bf16 W
  const bool usews = (ws_size >= wbytes);

  if (usews) {
    u16* wbf = (u16*)d_ws;
    const int total = NEXPERT * NOUT * KIN;  // 2,097,152
    conv_w_kernel<<<total / (256 * 4), 256, 0, stream>>>(w, wbf);
    moe_gemm_kernel<true><<<NTOK / BM, 256, 0, stream>>>(inp, w, wbf, counts, out);
  } else {
    moe_gemm_kernel<false><<<NTOK / BM, 256, 0, stream>>>(inp, w, nullptr, counts, out);
  }
}

// Round 5
// 219.745 us; speedup vs baseline: 2.3263x; 2.3263x over previous
//
#include <hip/hip_runtime.h>
#include <cstdint>
#include <cstddef>

#define NEXPERT 32
#define KIN 256
#define NOUT 256
#define NTOK 524288
#define BM 64

typedef float f32x4 __attribute__((ext_vector_type(4)));
typedef __bf16 bf16x8 __attribute__((ext_vector_type(8)));
typedef unsigned short u16;
typedef u16 u16x8 __attribute__((ext_vector_type(8)));
typedef unsigned int u32;

union BF8 { u16x8 u; bf16x8 b; };

__device__ __forceinline__ u16 f2bf(float f) {
  unsigned u = __float_as_uint(f);
  return (u16)((u + 0x7FFFu + ((u >> 16) & 1u)) >> 16);  // RNE
}

// global_load_lds width-16: LDS dest = wave-uniform base + lane*16,
// global source per-lane (pre-swizzled). AS3 cast via low-32 truncation.
#define GLDS(gp, lp) __builtin_amdgcn_global_load_lds(                      \
    (const __attribute__((address_space(1))) u32*)(gp),                      \
    (__attribute__((address_space(3))) u32*)(u32)(uintptr_t)(lp), 16, 0, 0)

#define VMW(n) asm volatile("s_waitcnt vmcnt(" n ")" ::: "memory")
#define BAR()  do { __builtin_amdgcn_sched_barrier(0);                       \
                    __builtin_amdgcn_s_barrier();                            \
                    __builtin_amdgcn_sched_barrier(0); } while (0)

// ---- prologue: pack W fp32 -> bf16 in MFMA-fragment order ----
// 16B unit index t = ((e*8 + kc)*16 + n16)*64 + lane;
// lane holds W[e][n16*16 + (lane&15)][kc*32 + (lane>>4)*8 + j], j=0..7.
__global__ void pack_w_kernel(const float* __restrict__ w, u16* __restrict__ wb) {
  const int t    = blockIdx.x * 256 + threadIdx.x;   // 0..262143
  const int lane = t & 63;
  const int n16  = (t >> 6) & 15;
  const int kc   = (t >> 10) & 7;
  const int e    = t >> 13;
  const float* src = w + (size_t)e * 65536 + (size_t)(n16 * 16 + (lane & 15)) * 256
                       + kc * 32 + (lane >> 4) * 8;
  const float4 a = *reinterpret_cast<const float4*>(src);
  const float4 b = *reinterpret_cast<const float4*>(src + 4);
  u16x8 h;
  h[0]=f2bf(a.x); h[1]=f2bf(a.y); h[2]=f2bf(a.z); h[3]=f2bf(a.w);
  h[4]=f2bf(b.x); h[5]=f2bf(b.y); h[6]=f2bf(b.z); h[7]=f2bf(b.w);
  *reinterpret_cast<u16x8*>(wb + (size_t)t * 8) = h;
}

// ---- B fragments for one K-step (2 chunks x 4 n), fully coalesced 1KB loads ----
template<bool WSBF>
__device__ __forceinline__ void loadBstep(const u16* wEL, const float* wF,
                                          int wv, int l15, int lg, int s,
                                          BF8 (&d)[2][4]) {
  if (WSBF) {
#pragma unroll
    for (int c = 0; c < 2; ++c)
#pragma unroll
      for (int n = 0; n < 4; ++n)
        d[c][n].u = *reinterpret_cast<const u16x8*>(
            wEL + (size_t)(((2 * s + c) * 16 + (wv << 2) + n)) * 512);
  } else {
#pragma unroll
    for (int c = 0; c < 2; ++c)
#pragma unroll
      for (int n = 0; n < 4; ++n) {
        const float4* p = reinterpret_cast<const float4*>(
            wF + (size_t)((wv << 6) + (n << 4) + l15) * KIN + (2 * s + c) * 32 + lg * 8);
        const float4 x = p[0], y = p[1];
        u16x8 h;
        h[0]=f2bf(x.x); h[1]=f2bf(x.y); h[2]=f2bf(x.z); h[3]=f2bf(x.w);
        h[4]=f2bf(y.x); h[5]=f2bf(y.y); h[6]=f2bf(y.z); h[7]=f2bf(y.w);
        d[c][n].u = h;
      }
  }
}

// ---- one K-step of MFMA from a staged fp32 LDS buffer (swizzled read) ----
__device__ __forceinline__ void computeStep(const char* sAc, int buf, int l15, int lg,
                                            const BF8 (&bfr)[2][4], f32x4 (&acc)[4][4]) {
  const char* abase = sAc + buf * 16384 + l15 * 256;
#pragma unroll
  for (int c = 0; c < 2; ++c) {
    BF8 af[4];
#pragma unroll
    for (int m = 0; m < 4; ++m) {
      const int g0 = (c << 3) + (lg << 1);
      const f32x4 fa = *reinterpret_cast<const f32x4*>(abase + m * 4096 + (((g0    ) ^ l15) << 4));
      const f32x4 fb = *reinterpret_cast<const f32x4*>(abase + m * 4096 + (((g0 + 1) ^ l15) << 4));
      af[m].b[0]=(__bf16)fa[0]; af[m].b[1]=(__bf16)fa[1];
      af[m].b[2]=(__bf16)fa[2]; af[m].b[3]=(__bf16)fa[3];
      af[m].b[4]=(__bf16)fb[0]; af[m].b[5]=(__bf16)fb[1];
      af[m].b[6]=(__bf16)fb[2]; af[m].b[7]=(__bf16)fb[3];
    }
#pragma unroll
    for (int m = 0; m < 4; ++m)
#pragma unroll
      for (int n = 0; n < 4; ++n)
        acc[m][n] = __builtin_amdgcn_mfma_f32_16x16x32_bf16(
            af[m].b, bfr[c][n].b, acc[m][n], 0, 0, 0);
  }
}

// ---- grouped GEMM: 64x256 tile, 4 waves, 4 K-steps of 64 ----
// A: global_load_lds fp32 into 4 LDS buffers (16KB each), source pre-swizzled
// (unit u' holds logical group u'^(row&15)); raw s_barrier + counted vmcnt.
template<bool WSBF>
__global__ __launch_bounds__(256)
void moe_gemm_kernel(const float* __restrict__ inp,
                     const float* w32,
                     const u16* __restrict__ wpk,
                     const int* __restrict__ counts,
                     float* __restrict__ out)
{
  __shared__ float sA[4 * 64 * 64];   // 64 KB

  const int tid  = threadIdx.x;
  const int lane = tid & 63;
  const int wv   = tid >> 6;
  const int l15  = lane & 15;
  const int lg   = lane >> 4;

  // per-wave cumsum of counts via shuffle scan (handles int32 or int64)
  const long long* c64 = reinterpret_cast<const long long*>(counts);
  const long long p0 = c64[0];
  const bool is64 = (p0 >= 0 && p0 < (1ll << 31));
  int c = 0;
  if (lane < 32) c = is64 ? (int)c64[lane] : counts[lane];
#pragma unroll
  for (int d = 1; d < 32; d <<= 1) {
    const int o = __shfl_up(c, d, 64);
    if (lane >= d) c += o;
  }
  const int cum = (lane < 32) ? c : 0x7fffffff;

  const int t0 = blockIdx.x * BM;
  const int t1 = t0 + BM;

  // stage source pointers: instr i covers rows wv*16+i*4 .. +4;
  // lane writes physical unit u'=lane&15 <- logical group g = u' ^ (row&15)
  const float* gp[4];
#pragma unroll
  for (int i = 0; i < 4; ++i) {
    const int r = (wv << 4) + (i << 2) + (lane >> 4);
    const int g = (lane & 15) ^ (r & 15);
    gp[i] = inp + (size_t)(t0 + r) * KIN + g * 4;
  }
  char* const sAc   = reinterpret_cast<char*>(sA);
  char* const lbase = sAc + wv * 4096;   // + buf*16384 + i*1024 (wave-uniform)

  int rb = t0;
  int e  = __popcll(__ballot(cum <= t0));

  while (rb < t1) {
    const int re = min(t1, __shfl(cum, e));
    if (re > rb) {
      const u16*   wEL = wpk + (size_t)e * 65536 + (lane << 3);
      const float* wF  = w32 + ((size_t)e << 16);

      f32x4 acc[4][4];
      const f32x4 zero = {0.f, 0.f, 0.f, 0.f};
#pragma unroll
      for (int m = 0; m < 4; ++m)
#pragma unroll
        for (int n = 0; n < 4; ++n) acc[m][n] = zero;

      BF8 breA[2][4], breB[2][4];

      // ---- prologue: B0 + stage buf0,buf1 (16 in flight) ----
      loadBstep<WSBF>(wEL, wF, wv, l15, lg, 0, breA);
#pragma unroll
      for (int i = 0; i < 4; ++i) GLDS(gp[i] +   0, lbase +     0 + i * 1024);
#pragma unroll
      for (int i = 0; i < 4; ++i) GLDS(gp[i] +  64, lbase + 16384 + i * 1024);

      // ---- I0: B1 + stage buf2; wait drains B0+L0 ----
      loadBstep<WSBF>(wEL, wF, wv, l15, lg, 1, breB);
#pragma unroll
      for (int i = 0; i < 4; ++i) GLDS(gp[i] + 128, lbase + 32768 + i * 1024);
      VMW("16"); BAR();
      computeStep(sAc, 0, l15, lg, breA, acc);

      // ---- I1: B2 + stage buf3; wait drains L1+B1 ----
      loadBstep<WSBF>(wEL, wF, wv, l15, lg, 2, breA);
#pragma unroll
      for (int i = 0; i < 4; ++i) GLDS(gp[i] + 192, lbase + 49152 + i * 1024);
      VMW("16"); BAR();
      computeStep(sAc, 1, l15, lg, breB, acc);

      // ---- I2: B3; wait drains L2+B2 ----
      loadBstep<WSBF>(wEL, wF, wv, l15, lg, 3, breB);
      VMW("12"); BAR();
      computeStep(sAc, 2, l15, lg, breA, acc);

      // ---- I3: tail ----
      VMW("0"); BAR();
      computeStep(sAc, 3, l15, lg, breB, acc);

      // ---- epilogue (C/D map: col=l15, row=lg*4+j) ----
      const bool full = (rb == t0) & (re == t1);
      if (full) {
#pragma unroll
        for (int m = 0; m < 4; ++m) {
          const int rbase = t0 + (m << 4) + (lg << 2);
#pragma unroll
          for (int n = 0; n < 4; ++n) {
            float* op = out + (size_t)rbase * NOUT + (wv << 6) + (n << 4) + l15;
#pragma unroll
            for (int j = 0; j < 4; ++j) op[(size_t)j * NOUT] = acc[m][n][j];
          }
        }
      } else {
#pragma unroll
        for (int m = 0; m < 4; ++m) {
          const int rbase = t0 + (m << 4) + (lg << 2);
#pragma unroll
          for (int n = 0; n < 4; ++n) {
            float* op = out + (size_t)rbase * NOUT + (wv << 6) + (n << 4) + l15;
#pragma unroll
            for (int j = 0; j < 4; ++j) {
              const int rg = rbase + j;
              if (rg >= rb && rg < re) op[(size_t)j * NOUT] = acc[m][n][j];
            }
          }
        }
      }
    }
    rb = re > rb ? re : rb;
    ++e;
  }
}

extern "C" void kernel_launch(void* const* d_in, const int* in_sizes, int n_in,
                              void* d_out, int out_size, void* d_ws, size_t ws_size,
                              hipStream_t stream) {
  const float* inp    = (const float*)d_in[0];
  const float* w      = (const float*)d_in[1];
  const int*   counts = (const int*)d_in[2];
  float*       out    = (float*)d_out;

  const size_t wbytes = (size_t)NEXPERT * NOUT * KIN * 2;  // 4 MB packed bf16 W
  const bool usews = (ws_size >= wbytes);

  if (usews) {
    u16* wpk = (u16*)d_ws;
    pack_w_kernel<<<1024, 256, 0, stream>>>(w, wpk);
    moe_gemm_kernel<true><<<NTOK / BM, 256, 0, stream>>>(inp, w, wpk, counts, out);
  } else {
    moe_gemm_kernel<false><<<NTOK / BM, 256, 0, stream>>>(inp, w, nullptr, counts, out);
  }
}